// Round 1
// baseline (71.652 us; speedup 1.0000x reference)
//
#include <hip/hip_runtime.h>

// Cubic B-spline eval on uniform extended grid.
// KNOTS=64, DEGREE=3 -> h = 2/63, extended grid len 70, coeffs used: 66.
// For x in [-1,1): j = floor((x+1)/h) in [0,62], t = frac; output =
//   b0(t)*c[j] + b1(t)*c[j+1] + b2(t)*c[j+2] + b3(t)*c[j+3]
// with the standard uniform cubic B-spline segment polynomials.

__global__ __launch_bounds__(256) void bspline_kernel(
    const float* __restrict__ x,
    const float* __restrict__ coeffs,
    float* __restrict__ out,
    int n4)
{
    __shared__ float sc[66];
    const int tid = threadIdx.x;
    if (tid < 66) sc[tid] = coeffs[tid];
    __syncthreads();

    const int idx = blockIdx.x * blockDim.x + tid;
    if (idx >= n4) return;

    const float4* __restrict__ x4 = (const float4*)x;
    float4* __restrict__ out4 = (float4*)out;

    float4 xv = x4[idx];
    float xs[4] = {xv.x, xv.y, xv.z, xv.w};
    float os[4];

    const float H_INV = 31.5f;           // (KNOTS-1)/2
    const float SIXTH = 1.0f / 6.0f;

#pragma unroll
    for (int k = 0; k < 4; ++k) {
        float u = (xs[k] + 1.0f) * H_INV;
        float fj = floorf(u);
        int j = (int)fj;
        j = min(max(j, 0), 62);
        float t = u - (float)j;
        float s = 1.0f - t;
        float t2 = t * t;
        float t3 = t2 * t;
        float w0 = s * s * s * SIXTH;
        float w1 = (3.0f * t3 - 6.0f * t2 + 4.0f) * SIXTH;
        float w2 = (-3.0f * t3 + 3.0f * t2 + 3.0f * t + 1.0f) * SIXTH;
        float w3 = t3 * SIXTH;
        os[k] = w0 * sc[j] + w1 * sc[j + 1] + w2 * sc[j + 2] + w3 * sc[j + 3];
    }

    float4 ov;
    ov.x = os[0]; ov.y = os[1]; ov.z = os[2]; ov.w = os[3];
    out4[idx] = ov;
}

extern "C" void kernel_launch(void* const* d_in, const int* in_sizes, int n_in,
                              void* d_out, int out_size, void* d_ws, size_t ws_size,
                              hipStream_t stream) {
    const float* x      = (const float*)d_in[0];
    const float* coeffs = (const float*)d_in[1];
    // d_in[2] is the grid buffer; it is uniform so we use the analytic h.
    float* out = (float*)d_out;

    int n = in_sizes[0];           // 4194304, multiple of 4
    int n4 = n >> 2;               // 1048576 float4 elements
    int block = 256;
    int grid = (n4 + block - 1) / block;  // 4096 blocks

    bspline_kernel<<<grid, block, 0, stream>>>(x, coeffs, out, n4);
}